// Round 8
// baseline (5536.639 us; speedup 1.0000x reference)
//
#include <hip/hip_runtime.h>
#include <hip/hip_bf16.h>
#include <cstdint>

// Problem constants (match setup_inputs)
constexpr int B  = 2;
constexpr int L  = 2048;
constexpr int S  = 2048;
constexpr int DM = 1024;
constexpr int H  = 16;
constexpr int R  = 32;     // rank
constexpr int DH = 64;     // head dim
constexpr int TOPK = 32;
constexpr int SELCAP = 36; // per-row selection capacity (>32 only on exact fp ties)
constexpr float SCALE = 0.17677669529663687f; // 1/sqrt(32)

// MEASURED (R4-R7): the backend sets the VGPR budget from LDS-implied
// occupancy (65 KB LDS -> 2 blocks/CU -> 4 waves/SIMD -> 128-VGPR cap),
// regardless of __launch_bounds__. Demand must fit UNDER that cap or the
// kernel spills to scratch (11-15 GB HBM traffic, 4-6x slowdown).
// v7: single-buffered K (no kb[8]) cuts demand ~32 VGPR to fit 128.

// ---------------------------------------------------------------------------
// Tiled fp32 GEMM: C[M,N] = (A[M,K] @ W[K,N] + bias[N]) * outScale  (unchanged)
// ---------------------------------------------------------------------------
__global__ __launch_bounds__(256, 2)
void gemm128_f32(const float* __restrict__ A, const float* __restrict__ W,
                 const float* __restrict__ bias, float* __restrict__ C,
                 int M, int N, int K, float outScale)
{
    __shared__ float As[16][136];
    __shared__ float Ws[16][132];

    const int t  = threadIdx.x;
    const int tx = t & 15;
    const int ty = t >> 4;
    const int m0 = blockIdx.y * 128;
    const int n0 = blockIdx.x * 128;

    float acc[8][8];
#pragma unroll
    for (int i = 0; i < 8; ++i)
#pragma unroll
        for (int j = 0; j < 8; ++j) acc[i][j] = 0.f;

    for (int kb = 0; kb < K; kb += 16) {
        __syncthreads();
#pragma unroll
        for (int it = 0; it < 2; ++it) {
            int f4  = t + it * 256;
            int row = f4 >> 2;
            int cg  = (f4 & 3) * 4;
            float4 av = *(const float4*)&A[(size_t)(m0 + row) * K + kb + cg];
            As[cg + 0][row] = av.x;
            As[cg + 1][row] = av.y;
            As[cg + 2][row] = av.z;
            As[cg + 3][row] = av.w;
        }
#pragma unroll
        for (int it = 0; it < 2; ++it) {
            int f4 = t + it * 256;
            int kk = f4 >> 5;
            int cb = (f4 & 31) * 4;
            *(float4*)&Ws[kk][cb] = *(const float4*)&W[(size_t)(kb + kk) * N + n0 + cb];
        }
        __syncthreads();
#pragma unroll
        for (int kk = 0; kk < 16; ++kk) {
            float4 a0 = *(const float4*)&As[kk][ty * 8];
            float4 a1 = *(const float4*)&As[kk][ty * 8 + 4];
            float4 w0 = *(const float4*)&Ws[kk][tx * 8];
            float4 w1 = *(const float4*)&Ws[kk][tx * 8 + 4];
            float a[8] = {a0.x, a0.y, a0.z, a0.w, a1.x, a1.y, a1.z, a1.w};
            float w[8] = {w0.x, w0.y, w0.z, w0.w, w1.x, w1.y, w1.z, w1.w};
#pragma unroll
            for (int i = 0; i < 8; ++i)
#pragma unroll
                for (int j = 0; j < 8; ++j)
                    acc[i][j] = fmaf(a[i], w[j], acc[i][j]);
        }
    }

    float4 b0 = *(const float4*)&bias[n0 + tx * 8];
    float4 b1 = *(const float4*)&bias[n0 + tx * 8 + 4];
#pragma unroll
    for (int i = 0; i < 8; ++i) {
        float4 o0 = make_float4((acc[i][0] + b0.x) * outScale, (acc[i][1] + b0.y) * outScale,
                                (acc[i][2] + b0.z) * outScale, (acc[i][3] + b0.w) * outScale);
        float4 o1 = make_float4((acc[i][4] + b1.x) * outScale, (acc[i][5] + b1.y) * outScale,
                                (acc[i][6] + b1.z) * outScale, (acc[i][7] + b1.w) * outScale);
        size_t off = (size_t)(m0 + ty * 8 + i) * N + n0 + tx * 8;
        *(float4*)&C[off]     = o0;
        *(float4*)&C[off + 4] = o1;
    }
}

// ---------------------------------------------------------------------------
// Kernel 1 (v7): 8 rows/block, Q via LDS float4 broadcast, K SINGLE-buffered
// (ka[8] only, 32 VGPR) so demand fits the 128-VGPR budget implied by
// 65 KB LDS / 2 blocks/CU / 4 waves/SIMD. #pragma unroll 1 on the chunk loop
// stops the compiler from re-creating a double buffer. TLP (4 waves/SIMD)
// hides the un-prefetched K load latency.
// FMA order identical to v4-v6 -> bit-identical output.
// ---------------------------------------------------------------------------
__global__ __launch_bounds__(512, 1)
void score_select(const float* __restrict__ Qp, const float* __restrict__ Kp,
                  unsigned short* __restrict__ selIdx, float* __restrict__ selWt,
                  int* __restrict__ selCnt, float* __restrict__ selInv)
{
    __shared__ float  sclds[8][2048];   // 64 KB
    __shared__ float4 Qlds4[8][8];      // 1 KB (pre-scaled Q)

    const int t    = threadIdx.x;
    const int lane = t & 63;
    const int wv   = t >> 6;            // 0..7

    // XCD-aware swizzle: all 256 tiles of one (b,h) land on one XCD
    const int wgid = blockIdx.x;
    const int xcd  = wgid & 7;
    const int jj   = wgid >> 3;              // 0..1023
    const int bh   = xcd + 8 * (jj >> 8);    // 0..31
    const int tile = jj & 255;
    const int b    = bh >> 4;
    const int h    = bh & 15;
    const int lbase = tile * 8;

    const float* kbase = Kp + (size_t)b * S * (H * R) + h * R;
    const float* qbase = Qp + (size_t)(b * L + lbase) * (H * R) + h * R;

    // stage Q tile (8 rows x 8 quads)
    if (t < 64) {
        int row = t >> 3, q = t & 7;
        Qlds4[row][q] = *(const float4*)(qbase + (size_t)row * (H * R) + q * 4);
    }
    __syncthreads();   // Qlds4 ready

    // ---- score phase: 4 chunks of 512 keys; K single-buffered in VGPRs ----
#pragma unroll 1
    for (int c = 0; c < 4; ++c) {
        float4 ka[8];
        const float* kp = kbase + (size_t)(c * 512 + wv * 64 + lane) * (H * R);
#pragma unroll
        for (int q = 0; q < 8; ++q) ka[q] = *(const float4*)(kp + q * 4);

        const int keyl = c * 512 + wv * 64 + lane;
#pragma unroll
        for (int r = 0; r < 8; ++r) {
            float s = 0.f;
#pragma unroll
            for (int q = 0; q < 8; ++q) {
                float4 qv = Qlds4[r][q];           // wave-uniform broadcast
                s = fmaf(qv.x, ka[q].x, s);
                s = fmaf(qv.y, ka[q].y, s);
                s = fmaf(qv.z, ka[q].z, s);
                s = fmaf(qv.w, ka[q].w, s);
            }
            sclds[r][keyl] = s;
        }
    }

    __syncthreads();

    // ---- selection: wave wv handles row wv ----
    const unsigned long long lanelt = (1ull << lane) - 1ull;
    {
        const int r     = wv;
        const int row_g = bh * L + lbase + r;

        float sreg[32];
#pragma unroll
        for (int j = 0; j < 32; ++j) sreg[j] = sclds[r][j * 64 + lane];

        // row max (float domain)
        float mx = sreg[0];
#pragma unroll
        for (int j = 1; j < 32; ++j) mx = fmaxf(mx, sreg[j]);
#pragma unroll
        for (int off = 32; off >= 1; off >>= 1)
            mx = fmaxf(mx, __shfl_xor(mx, off, 64));

        // in-place sortable-uint conversion (monotone bijection)
#pragma unroll
        for (int j = 0; j < 32; ++j) {
            unsigned int bb  = __float_as_uint(sreg[j]);
            unsigned int sgn = (unsigned int)(((int)bb) >> 31);
            sreg[j] = __uint_as_float(bb ^ (sgn | 0x80000000u));
        }

        // MSB radix select with exact-count early exit
        unsigned int P = 0;
        for (int bit = 31; bit >= 0; --bit) {
            unsigned int test = P | (1u << bit);
            int c2 = 0;
#pragma unroll
            for (int j = 0; j < 32; ++j)
                c2 += (int)__popcll(__ballot(__float_as_uint(sreg[j]) >= test));
            if (c2 >= TOPK) {
                P = test;
                if (c2 == TOPK) break;
            }
        }

        // single exp pass: emit (idx, unnormalized weight) + denominator
        float dsum = 0.f;
        int   base = 0;
#pragma unroll
        for (int j = 0; j < 32; ++j) {
            unsigned int u = __float_as_uint(sreg[j]);
            bool sel = (u >= P);
            unsigned int sg2  = (unsigned int)(((int)u) >> 31);
            unsigned int mask = 0x80000000u | ~sg2;
            float forig = __uint_as_float(u ^ mask);
            float e = __expf(forig - mx);
            unsigned long long m = __ballot(sel);
            if (sel) {
                int pos = base + (int)__popcll(m & lanelt);
                if (pos < SELCAP) {
                    selIdx[(size_t)row_g * SELCAP + pos] = (unsigned short)(j * 64 + lane);
                    selWt[(size_t)row_g * SELCAP + pos] = e;
                }
            }
            dsum += sel ? e : 0.f;
            base += (int)__popcll(m);
        }
#pragma unroll
        for (int off = 32; off >= 1; off >>= 1)
            dsum += __shfl_xor(dsum, off, 64);
        if (lane == 0) {
            selInv[row_g] = 1.0f / dsum;
            selCnt[row_g] = base < SELCAP ? base : SELCAP;
        }
    }
}

// ---------------------------------------------------------------------------
// Kernel 2: sparse PV gather (unchanged). One wave per row, lane = output dim.
// ---------------------------------------------------------------------------
__global__ __launch_bounds__(256)
void pv_gather(const float* __restrict__ Vp, const unsigned short* __restrict__ selIdx,
               const float* __restrict__ selWt, const int* __restrict__ selCnt,
               const float* __restrict__ selInv, float* __restrict__ Oh)
{
    const int t    = threadIdx.x;
    const int lane = t & 63;
    const int wv   = t >> 6;

    const int wg   = blockIdx.x;              // 0..16383
    const int xcd  = wg & 7;
    const int jj   = wg >> 3;                 // 0..2047
    const int bh   = xcd + 8 * (jj >> 9);     // 0..31
    const int tile = jj & 511;
    const int b    = bh >> 4;
    const int h    = bh & 15;
    const int l    = tile * 4 + wv;
    const int row_g = bh * L + l;

    int   cn  = selCnt[row_g];
    cn = cn < SELCAP ? cn : SELCAP;
    const float inv = selInv[row_g];
    const float* vb = Vp + (size_t)b * S * DM + h * DH + lane;
    const unsigned short* si = selIdx + (size_t)row_g * SELCAP;
    const float*          sw = selWt  + (size_t)row_g * SELCAP;

    float a0 = 0.f, a1 = 0.f, a2 = 0.f, a3 = 0.f;
    int tt = 0;
    for (; tt + 4 <= cn; tt += 4) {
        int   s0 = si[tt + 0], s1 = si[tt + 1], s2 = si[tt + 2], s3 = si[tt + 3];
        float w0 = sw[tt + 0], w1 = sw[tt + 1], w2 = sw[tt + 2], w3 = sw[tt + 3];
        a0 = fmaf(w0, vb[(size_t)s0 * DM], a0);
        a1 = fmaf(w1, vb[(size_t)s1 * DM], a1);
        a2 = fmaf(w2, vb[(size_t)s2 * DM], a2);
        a3 = fmaf(w3, vb[(size_t)s3 * DM], a3);
    }
    for (; tt < cn; ++tt) {
        int s0 = si[tt];
        a0 = fmaf(sw[tt], vb[(size_t)s0 * DM], a0);
    }
    Oh[(size_t)(b * L + l) * DM + h * DH + lane] = ((a0 + a1) + (a2 + a3)) * inv;
}

// ---------------------------------------------------------------------------
extern "C" void kernel_launch(void* const* d_in, const int* in_sizes, int n_in,
                              void* d_out, int out_size, void* d_ws, size_t ws_size,
                              hipStream_t stream)
{
    const float* q  = (const float*)d_in[0];
    const float* k  = (const float*)d_in[1];
    const float* v  = (const float*)d_in[2];
    const float* Wq = (const float*)d_in[3];
    const float* bq = (const float*)d_in[4];
    const float* Wk = (const float*)d_in[5];
    const float* bk = (const float*)d_in[6];
    const float* Wv = (const float*)d_in[7];
    const float* bv = (const float*)d_in[8];
    const float* Wo = (const float*)d_in[9];
    const float* bo = (const float*)d_in[10];
    // d_in[11] = pos_bias: per-head additive constant -> top-k/softmax invariant -> no-op.

    float* out = (float*)d_out;
    char*  ws  = (char*)d_ws;

    const size_t MB = 1024 * 1024;
    float* Qp = (float*)(ws);             //  8 MiB: (B*L, 512)  (pre-scaled by 1/sqrt(R))
    float* Kp = (float*)(ws + 8  * MB);   //  8 MiB: (B*S, 512)
    float* Vp = (float*)(ws + 16 * MB);   // 16 MiB: (B*S, 1024)
    float* Oh = (float*)(ws + 32 * MB);   // 16 MiB: (B*L, 1024)
    unsigned short* selIdx = (unsigned short*)(ws + 48 * MB);     // 4.72 MiB
    float*          selWt  = (float*)(ws + 53 * MB);              // 9.44 MiB
    int*            selCnt = (int*)(ws + 63 * MB);                // 0.25 MiB
    float*          selInv = (float*)(ws + 63 * MB + 512 * 1024); // 0.25 MiB

    const int M = B * L;  // 4096
    dim3 blk(256);

    gemm128_f32<<<dim3((H * R) / 128, M / 128), blk, 0, stream>>>(q, Wq, bq, Qp, M, H * R, DM, SCALE);
    gemm128_f32<<<dim3((H * R) / 128, M / 128), blk, 0, stream>>>(k, Wk, bk, Kp, M, H * R, DM, 1.0f);
    gemm128_f32<<<dim3(DM / 128, M / 128),      blk, 0, stream>>>(v, Wv, bv, Vp, M, DM, DM, 1.0f);

    score_select<<<dim3(8192), dim3(512), 0, stream>>>(Qp, Kp, selIdx, selWt, selCnt, selInv);
    pv_gather  <<<dim3(16384), blk, 0, stream>>>(Vp, selIdx, selWt, selCnt, selInv, Oh);

    gemm128_f32<<<dim3(DM / 128, M / 128),      blk, 0, stream>>>(Oh, Wo, bo, out, M, DM, DM, 1.0f);
}

// Round 9
// 895.235 us; speedup vs baseline: 6.1846x; 6.1846x over previous
//
#include <hip/hip_runtime.h>
#include <hip/hip_bf16.h>
#include <cstdint>

// Problem constants (match setup_inputs)
constexpr int B  = 2;
constexpr int L  = 2048;
constexpr int S  = 2048;
constexpr int DM = 1024;
constexpr int H  = 16;
constexpr int R  = 32;     // rank
constexpr int DH = 64;     // head dim
constexpr int TOPK = 32;
constexpr int SELCAP = 36; // per-row selection capacity (>32 only on exact fp ties)
constexpr float SCALE = 0.17677669529663687f; // 1/sqrt(32)

// MEASURED (R4-R8): the backend budgets VGPRs from LDS-implied occupancy
// (64KB LDS -> 2 blocks/CU -> 128-VGPR cap). R6-R8 spilled because LICM
// hoisted the 64 loop-invariant float4 Q-broadcast reads out of the chunk
// loop (256-VGPR demand; scratch = 5.5 GB writes ~= 328 floats/thread).
// Fix: opaque-zero asm redefined per chunk in the Q row index -> no hoist.

// ---------------------------------------------------------------------------
// Tiled fp32 GEMM: C[M,N] = (A[M,K] @ W[K,N] + bias[N]) * outScale  (unchanged)
// ---------------------------------------------------------------------------
__global__ __launch_bounds__(256, 2)
void gemm128_f32(const float* __restrict__ A, const float* __restrict__ W,
                 const float* __restrict__ bias, float* __restrict__ C,
                 int M, int N, int K, float outScale)
{
    __shared__ float As[16][136];
    __shared__ float Ws[16][132];

    const int t  = threadIdx.x;
    const int tx = t & 15;
    const int ty = t >> 4;
    const int m0 = blockIdx.y * 128;
    const int n0 = blockIdx.x * 128;

    float acc[8][8];
#pragma unroll
    for (int i = 0; i < 8; ++i)
#pragma unroll
        for (int j = 0; j < 8; ++j) acc[i][j] = 0.f;

    for (int kb = 0; kb < K; kb += 16) {
        __syncthreads();
#pragma unroll
        for (int it = 0; it < 2; ++it) {
            int f4  = t + it * 256;
            int row = f4 >> 2;
            int cg  = (f4 & 3) * 4;
            float4 av = *(const float4*)&A[(size_t)(m0 + row) * K + kb + cg];
            As[cg + 0][row] = av.x;
            As[cg + 1][row] = av.y;
            As[cg + 2][row] = av.z;
            As[cg + 3][row] = av.w;
        }
#pragma unroll
        for (int it = 0; it < 2; ++it) {
            int f4 = t + it * 256;
            int kk = f4 >> 5;
            int cb = (f4 & 31) * 4;
            *(float4*)&Ws[kk][cb] = *(const float4*)&W[(size_t)(kb + kk) * N + n0 + cb];
        }
        __syncthreads();
#pragma unroll
        for (int kk = 0; kk < 16; ++kk) {
            float4 a0 = *(const float4*)&As[kk][ty * 8];
            float4 a1 = *(const float4*)&As[kk][ty * 8 + 4];
            float4 w0 = *(const float4*)&Ws[kk][tx * 8];
            float4 w1 = *(const float4*)&Ws[kk][tx * 8 + 4];
            float a[8] = {a0.x, a0.y, a0.z, a0.w, a1.x, a1.y, a1.z, a1.w};
            float w[8] = {w0.x, w0.y, w0.z, w0.w, w1.x, w1.y, w1.z, w1.w};
#pragma unroll
            for (int i = 0; i < 8; ++i)
#pragma unroll
                for (int j = 0; j < 8; ++j)
                    acc[i][j] = fmaf(a[i], w[j], acc[i][j]);
        }
    }

    float4 b0 = *(const float4*)&bias[n0 + tx * 8];
    float4 b1 = *(const float4*)&bias[n0 + tx * 8 + 4];
#pragma unroll
    for (int i = 0; i < 8; ++i) {
        float4 o0 = make_float4((acc[i][0] + b0.x) * outScale, (acc[i][1] + b0.y) * outScale,
                                (acc[i][2] + b0.z) * outScale, (acc[i][3] + b0.w) * outScale);
        float4 o1 = make_float4((acc[i][4] + b1.x) * outScale, (acc[i][5] + b1.y) * outScale,
                                (acc[i][6] + b1.z) * outScale, (acc[i][7] + b1.w) * outScale);
        size_t off = (size_t)(m0 + ty * 8 + i) * N + n0 + tx * 8;
        *(float4*)&C[off]     = o0;
        *(float4*)&C[off + 4] = o1;
    }
}

// ---------------------------------------------------------------------------
// Kernel 1 (v8): 8 rows/block, 64KB score LDS (2 blocks/CU, 4 waves/SIMD),
// K single-buffered (ka[8] = 32 VGPR), Q via LDS float4 broadcast with an
// ANTI-LICM opaque-zero row index so the 64 Q reads are NOT hoisted out of
// the chunk loop (the R6-R8 spill cause). Demand ~60-80 VGPR < 128 cap.
// FMA order identical to v4-v7 -> bit-identical output.
// ---------------------------------------------------------------------------
__global__ __launch_bounds__(512, 1)
void score_select(const float* __restrict__ Qp, const float* __restrict__ Kp,
                  unsigned short* __restrict__ selIdx, float* __restrict__ selWt,
                  int* __restrict__ selCnt, float* __restrict__ selInv)
{
    __shared__ float  sclds[8][2048];   // 64 KB
    __shared__ float4 Qlds4[8][8];      // 1 KB (pre-scaled Q)

    const int t    = threadIdx.x;
    const int lane = t & 63;
    const int wv   = t >> 6;            // 0..7

    // XCD-aware swizzle: all 256 tiles of one (b,h) land on one XCD
    const int wgid = blockIdx.x;
    const int xcd  = wgid & 7;
    const int jj   = wgid >> 3;              // 0..1023
    const int bh   = xcd + 8 * (jj >> 8);    // 0..31
    const int tile = jj & 255;
    const int b    = bh >> 4;
    const int h    = bh & 15;
    const int lbase = tile * 8;

    const float* kbase = Kp + (size_t)b * S * (H * R) + h * R;
    const float* qbase = Qp + (size_t)(b * L + lbase) * (H * R) + h * R;

    // stage Q tile (8 rows x 8 quads)
    if (t < 64) {
        int row = t >> 3, q = t & 7;
        Qlds4[row][q] = *(const float4*)(qbase + (size_t)row * (H * R) + q * 4);
    }
    __syncthreads();   // Qlds4 ready

    // ---- score phase: 4 chunks of 512 keys; K single-buffered in VGPRs ----
#pragma unroll 1
    for (int c = 0; c < 4; ++c) {
        float4 ka[8];
        const float* kp = kbase + (size_t)(c * 512 + wv * 64 + lane) * (H * R);
#pragma unroll
        for (int q = 0; q < 8; ++q) ka[q] = *(const float4*)(kp + q * 4);

        // ANTI-LICM: opaque zero, redefined every chunk. Q row index depends
        // on it, so the Qlds4 reads cannot be hoisted out of the c-loop.
        int zero;
        asm volatile("v_mov_b32 %0, 0" : "=v"(zero));

        const int keyl = c * 512 + wv * 64 + lane;
#pragma unroll
        for (int r = 0; r < 8; ++r) {
            const float4* qrow = Qlds4[r + zero];   // runtime row, per-q offsets fold into ds_read imm
            float s = 0.f;
#pragma unroll
            for (int q = 0; q < 8; ++q) {
                float4 qv = qrow[q];                // wave-uniform broadcast
                s = fmaf(qv.x, ka[q].x, s);
                s = fmaf(qv.y, ka[q].y, s);
                s = fmaf(qv.z, ka[q].z, s);
                s = fmaf(qv.w, ka[q].w, s);
            }
            sclds[r][keyl] = s;
        }
    }

    __syncthreads();

    // ---- selection: wave wv handles row wv ----
    const unsigned long long lanelt = (1ull << lane) - 1ull;
    {
        const int r     = wv;
        const int row_g = bh * L + lbase + r;

        float sreg[32];
#pragma unroll
        for (int j = 0; j < 32; ++j) sreg[j] = sclds[r][j * 64 + lane];

        // row max (float domain)
        float mx = sreg[0];
#pragma unroll
        for (int j = 1; j < 32; ++j) mx = fmaxf(mx, sreg[j]);
#pragma unroll
        for (int off = 32; off >= 1; off >>= 1)
            mx = fmaxf(mx, __shfl_xor(mx, off, 64));

        // in-place sortable-uint conversion (monotone bijection)
#pragma unroll
        for (int j = 0; j < 32; ++j) {
            unsigned int bb  = __float_as_uint(sreg[j]);
            unsigned int sgn = (unsigned int)(((int)bb) >> 31);
            sreg[j] = __uint_as_float(bb ^ (sgn | 0x80000000u));
        }

        // MSB radix select with exact-count early exit
        unsigned int P = 0;
        for (int bit = 31; bit >= 0; --bit) {
            unsigned int test = P | (1u << bit);
            int c2 = 0;
#pragma unroll
            for (int j = 0; j < 32; ++j)
                c2 += (int)__popcll(__ballot(__float_as_uint(sreg[j]) >= test));
            if (c2 >= TOPK) {
                P = test;
                if (c2 == TOPK) break;
            }
        }

        // single exp pass: emit (idx, unnormalized weight) + denominator
        float dsum = 0.f;
        int   base = 0;
#pragma unroll
        for (int j = 0; j < 32; ++j) {
            unsigned int u = __float_as_uint(sreg[j]);
            bool sel = (u >= P);
            unsigned int sg2  = (unsigned int)(((int)u) >> 31);
            unsigned int mask = 0x80000000u | ~sg2;
            float forig = __uint_as_float(u ^ mask);
            float e = __expf(forig - mx);
            unsigned long long m = __ballot(sel);
            if (sel) {
                int pos = base + (int)__popcll(m & lanelt);
                if (pos < SELCAP) {
                    selIdx[(size_t)row_g * SELCAP + pos] = (unsigned short)(j * 64 + lane);
                    selWt[(size_t)row_g * SELCAP + pos] = e;
                }
            }
            dsum += sel ? e : 0.f;
            base += (int)__popcll(m);
        }
#pragma unroll
        for (int off = 32; off >= 1; off >>= 1)
            dsum += __shfl_xor(dsum, off, 64);
        if (lane == 0) {
            selInv[row_g] = 1.0f / dsum;
            selCnt[row_g] = base < SELCAP ? base : SELCAP;
        }
    }
}

// ---------------------------------------------------------------------------
// Kernel 2: sparse PV gather (unchanged). One wave per row, lane = output dim.
// ---------------------------------------------------------------------------
__global__ __launch_bounds__(256)
void pv_gather(const float* __restrict__ Vp, const unsigned short* __restrict__ selIdx,
               const float* __restrict__ selWt, const int* __restrict__ selCnt,
               const float* __restrict__ selInv, float* __restrict__ Oh)
{
    const int t    = threadIdx.x;
    const int lane = t & 63;
    const int wv   = t >> 6;

    const int wg   = blockIdx.x;              // 0..16383
    const int xcd  = wg & 7;
    const int jj   = wg >> 3;                 // 0..2047
    const int bh   = xcd + 8 * (jj >> 9);     // 0..31
    const int tile = jj & 511;
    const int b    = bh >> 4;
    const int h    = bh & 15;
    const int l    = tile * 4 + wv;
    const int row_g = bh * L + l;

    int   cn  = selCnt[row_g];
    cn = cn < SELCAP ? cn : SELCAP;
    const float inv = selInv[row_g];
    const float* vb = Vp + (size_t)b * S * DM + h * DH + lane;
    const unsigned short* si = selIdx + (size_t)row_g * SELCAP;
    const float*          sw = selWt  + (size_t)row_g * SELCAP;

    float a0 = 0.f, a1 = 0.f, a2 = 0.f, a3 = 0.f;
    int tt = 0;
    for (; tt + 4 <= cn; tt += 4) {
        int   s0 = si[tt + 0], s1 = si[tt + 1], s2 = si[tt + 2], s3 = si[tt + 3];
        float w0 = sw[tt + 0], w1 = sw[tt + 1], w2 = sw[tt + 2], w3 = sw[tt + 3];
        a0 = fmaf(w0, vb[(size_t)s0 * DM], a0);
        a1 = fmaf(w1, vb[(size_t)s1 * DM], a1);
        a2 = fmaf(w2, vb[(size_t)s2 * DM], a2);
        a3 = fmaf(w3, vb[(size_t)s3 * DM], a3);
    }
    for (; tt < cn; ++tt) {
        int s0 = si[tt];
        a0 = fmaf(sw[tt], vb[(size_t)s0 * DM], a0);
    }
    Oh[(size_t)(b * L + l) * DM + h * DH + lane] = ((a0 + a1) + (a2 + a3)) * inv;
}

// ---------------------------------------------------------------------------
extern "C" void kernel_launch(void* const* d_in, const int* in_sizes, int n_in,
                              void* d_out, int out_size, void* d_ws, size_t ws_size,
                              hipStream_t stream)
{
    const float* q  = (const float*)d_in[0];
    const float* k  = (const float*)d_in[1];
    const float* v  = (const float*)d_in[2];
    const float* Wq = (const float*)d_in[3];
    const float* bq = (const float*)d_in[4];
    const float* Wk = (const float*)d_in[5];
    const float* bk = (const float*)d_in[6];
    const float* Wv = (const float*)d_in[7];
    const float* bv = (const float*)d_in[8];
    const float* Wo = (const float*)d_in[9];
    const float* bo = (const float*)d_in[10];
    // d_in[11] = pos_bias: per-head additive constant -> top-k/softmax invariant -> no-op.

    float* out = (float*)d_out;
    char*  ws  = (char*)d_ws;

    const size_t MB = 1024 * 1024;
    float* Qp = (float*)(ws);             //  8 MiB: (B*L, 512)  (pre-scaled by 1/sqrt(R))
    float* Kp = (float*)(ws + 8  * MB);   //  8 MiB: (B*S, 512)
    float* Vp = (float*)(ws + 16 * MB);   // 16 MiB: (B*S, 1024)
    float* Oh = (float*)(ws + 32 * MB);   // 16 MiB: (B*L, 1024)
    unsigned short* selIdx = (unsigned short*)(ws + 48 * MB);     // 4.72 MiB
    float*          selWt  = (float*)(ws + 53 * MB);              // 9.44 MiB
    int*            selCnt = (int*)(ws + 63 * MB);                // 0.25 MiB
    float*          selInv = (float*)(ws + 63 * MB + 512 * 1024); // 0.25 MiB

    const int M = B * L;  // 4096
    dim3 blk(256);

    gemm128_f32<<<dim3((H * R) / 128, M / 128), blk, 0, stream>>>(q, Wq, bq, Qp, M, H * R, DM, SCALE);
    gemm128_f32<<<dim3((H * R) / 128, M / 128), blk, 0, stream>>>(k, Wk, bk, Kp, M, H * R, DM, 1.0f);
    gemm128_f32<<<dim3(DM / 128, M / 128),      blk, 0, stream>>>(v, Wv, bv, Vp, M, DM, DM, 1.0f);

    score_select<<<dim3(8192), dim3(512), 0, stream>>>(Qp, Kp, selIdx, selWt, selCnt, selInv);
    pv_gather  <<<dim3(16384), blk, 0, stream>>>(Vp, selIdx, selWt, selCnt, selInv, Oh);

    gemm128_f32<<<dim3(DM / 128, M / 128),      blk, 0, stream>>>(Oh, Wo, bo, out, M, DM, DM, 1.0f);
}